// Round 15
// baseline (110.094 us; speedup 1.0000x reference)
//
#include <hip/hip_runtime.h>
#include <hip/hip_bf16.h>

typedef __attribute__((ext_vector_type(8))) short bf16x8;
typedef __attribute__((ext_vector_type(4))) float f32x4;
typedef __attribute__((ext_vector_type(16))) float f32x16;
typedef unsigned short u16;

#define MFMA16(A,B,C) __builtin_amdgcn_mfma_f32_16x16x32_bf16(A,B,C,0,0,0)
#define MFMA32(A,B,C) __builtin_amdgcn_mfma_f32_32x32x16_bf16(A,B,C,0,0,0)

__device__ __forceinline__ u16 f2bf(float f) {
    union { float f; unsigned u; } x{f};
    unsigned r = x.u + 0x7FFFu + ((x.u >> 16) & 1u);
    return (u16)(r >> 16);
}

__device__ __forceinline__ unsigned cvtpk(float lo, float hi) {
    unsigned r;
    asm("v_cvt_pk_bf16_f32 %0, %1, %2" : "=v"(r) : "v"(lo), "v"(hi));
    return r;
}

__device__ __forceinline__ float fexp2(float x) {
#if __has_builtin(__builtin_amdgcn_exp2f)
    return __builtin_amdgcn_exp2f(x);   // bare v_exp_f32; inputs |x|<~30, no denormal path needed
#else
    return exp2f(x);
#endif
}

__device__ __forceinline__ void gload16(const void* src, void* dst) {
    __builtin_amdgcn_global_load_lds((const __attribute__((address_space(1))) void*)src,
                                     (__attribute__((address_space(3))) void*)dst, 16, 0, 0);
}

// cross-half exchange: j0 = [lo.low32 | hi2.low32], j2 = [lo.high32 | hi2.high32]
__device__ __forceinline__ void xhalf(unsigned lo, unsigned hi2, int hf, unsigned& j0, unsigned& j2) {
#if __has_builtin(__builtin_amdgcn_permlane32_swap)
    auto r = __builtin_amdgcn_permlane32_swap(lo, hi2, false, false);
    j0 = r[0]; j2 = r[1];
#else
    unsigned olo = (unsigned)__shfl_xor((int)lo, 32);
    unsigned ohi = (unsigned)__shfl_xor((int)hi2, 32);
    j0 = hf ? ohi : lo;
    j2 = hf ? hi2 : olo;
#endif
}

// ---- single fused f32 -> bf16 converter: inputs (3x 4M) + weights (4x 1M) ----
__global__ __launch_bounds__(256)
void cvt_all(const float* __restrict__ q, const float* __restrict__ k, const float* __restrict__ v,
             const float* __restrict__ Wq, const float* __restrict__ Wk,
             const float* __restrict__ Wv, const float* __restrict__ Wo,
             u16* __restrict__ oq, u16* __restrict__ ok, u16* __restrict__ ov,
             u16* __restrict__ ow) {
    int blk = blockIdx.x;
    const float* s;
    u16* o;
    if (blk < 6144) {
        int which = blk >> 11, lb = blk & 2047;
        s = (which == 0 ? q : (which == 1 ? k : v)) + (size_t)lb * 2048;
        o = (which == 0 ? oq : (which == 1 ? ok : ov)) + (size_t)lb * 2048;
    } else {
        int wblk = blk - 6144;          // 0..2047
        int which = wblk >> 9, lb = wblk & 511;
        s = (which == 0 ? Wq : (which == 1 ? Wk : (which == 2 ? Wv : Wo))) + (size_t)lb * 2048;
        o = ow + (size_t)which * 1048576 + (size_t)lb * 2048;
    }
    size_t base = (size_t)threadIdx.x * 8;
    float4 v0 = *(const float4*)(s + base);
    float4 v1 = *(const float4*)(s + base + 4);
    bf16x8 rv;
    rv[0] = (short)f2bf(v0.x); rv[1] = (short)f2bf(v0.y); rv[2] = (short)f2bf(v0.z); rv[3] = (short)f2bf(v0.w);
    rv[4] = (short)f2bf(v1.x); rv[5] = (short)f2bf(v1.y); rv[6] = (short)f2bf(v1.z); rv[7] = (short)f2bf(v1.w);
    *(bf16x8*)(o + base) = rv;
}

// ---- bf16 MFMA GEMM body: 128x64 tile, BK=64, double-buffered, prefetch-first ----
// (used by gemm_o: 512-block grid keeps 3 blocks/CU)
__device__ __forceinline__ void gemm_body(u16* gsm, const u16* __restrict__ A, const u16* __restrict__ W,
                                          const float* __restrict__ bias, float* __restrict__ Cout,
                                          int bm, int bn) {
    u16* Asl = gsm;            // 2 x 8192 u16
    u16* Wsl = gsm + 16384;    // 2 x 4096 u16
    const int t = threadIdx.x;
    const int lane = t & 63, w = t >> 6;
    const int g = lane >> 4, c = lane & 15;
    const int wr = (w >> 1) * 64, wc = (w & 1) * 32;

    f32x4 acc[4][2];
    #pragma unroll
    for (int i = 0; i < 4; ++i) {
        acc[i][0] = f32x4{0.f, 0.f, 0.f, 0.f};
        acc[i][1] = f32x4{0.f, 0.f, 0.f, 0.f};
    }

#define GS(buf, k0)                                                                         \
    {                                                                                       \
        _Pragma("unroll")                                                                   \
        for (int i = 0; i < 4; ++i) {                                                       \
            int off = i * 4096 + w * 1024 + lane * 16;                                      \
            int row = off >> 7, sl = (off >> 4) & 7;                                        \
            gload16(A + (size_t)(bm + row) * 1024 + (k0) + ((sl ^ (row & 7)) << 3),         \
                    Asl + (buf) * 8192 + i * 2048 + w * 512);                               \
        }                                                                                   \
        _Pragma("unroll")                                                                   \
        for (int i = 0; i < 2; ++i) {                                                       \
            int off = i * 4096 + w * 1024 + lane * 16;                                      \
            int row = off >> 7, sl = (off >> 4) & 7;                                        \
            gload16(W + (size_t)(bn + row) * 1024 + (k0) + ((sl ^ (row & 7)) << 3),         \
                    Wsl + (buf) * 4096 + i * 2048 + w * 512);                               \
        }                                                                                   \
    }

    GS(0, 0);
    __syncthreads();
    int cur = 0;

    for (int k0 = 0; k0 < 1024; k0 += 64) {
        if (k0 < 960) GS(cur ^ 1, k0 + 64);
        #pragma unroll
        for (int ks = 0; ks < 2; ++ks) {
            bf16x8 af[4], bfr[2];
            #pragma unroll
            for (int rf = 0; rf < 4; ++rf) {
                int row = wr + rf * 16 + c;
                int col = (ks * 64 + g * 16) ^ ((row & 7) << 4);
                af[rf] = *(const bf16x8*)((const char*)Asl + cur * 16384 + row * 128 + col);
            }
            #pragma unroll
            for (int cf = 0; cf < 2; ++cf) {
                int row = wc + cf * 16 + c;
                int col = (ks * 64 + g * 16) ^ ((row & 7) << 4);
                bfr[cf] = *(const bf16x8*)((const char*)Wsl + cur * 8192 + row * 128 + col);
            }
            __builtin_amdgcn_s_setprio(1);
            #pragma unroll
            for (int rf = 0; rf < 4; ++rf)
                #pragma unroll
                for (int cf = 0; cf < 2; ++cf)
                    acc[rf][cf] = MFMA16(af[rf], bfr[cf], acc[rf][cf]);
            __builtin_amdgcn_s_setprio(0);
        }
        __syncthreads();
        cur ^= 1;
    }
#undef GS

    #pragma unroll
    for (int rf = 0; rf < 4; ++rf) {
        #pragma unroll
        for (int cf = 0; cf < 2; ++cf) {
            int nCol = bn + wc + cf * 16 + c;
            float bv = bias[nCol];
            #pragma unroll
            for (int r = 0; r < 4; ++r) {
                int row = bm + wr + rf * 16 + 4 * g + r;
                Cout[(size_t)row * 1024 + nCol] = acc[rf][cf][r] + bv;
            }
        }
    }
}

// ---- bf16 MFMA GEMM body 2b: 128x128 tile, BK=64, A dbuf + W single-buffer ----
// LDS 48KB -> 3 blocks/CU; 768 tiles = exactly one residency round.
// MODE: 0 = bf16 out (scaled), 2 = bf16 per-head-transposed out (Vt layout).
template<int MODE>
__device__ __forceinline__ void gemm_body2(u16* gsm, const u16* __restrict__ A, const u16* __restrict__ W,
                                           const float* __restrict__ bias, u16* __restrict__ Cout,
                                           float scale, int bm, int bn) {
    u16* Asl = gsm;            // 2 x 8192 u16 (A dbuf, 32KB)
    u16* Wsl = gsm + 16384;    // 8192 u16 (W single, 16KB)
    const int t = threadIdx.x;
    const int lane = t & 63, w = t >> 6;
    const int g = lane >> 4, c = lane & 15;
    const int wr = (w >> 1) * 64, wc = (w & 1) * 64;

    f32x4 acc[4][4];
    #pragma unroll
    for (int i = 0; i < 4; ++i)
        #pragma unroll
        for (int j = 0; j < 4; ++j) acc[i][j] = f32x4{0.f, 0.f, 0.f, 0.f};

#define GSA(buf, k0)                                                                        \
    {                                                                                       \
        _Pragma("unroll")                                                                   \
        for (int i = 0; i < 4; ++i) {                                                       \
            int off = i * 4096 + w * 1024 + lane * 16;                                      \
            int row = off >> 7, sl = (off >> 4) & 7;                                        \
            gload16(A + (size_t)(bm + row) * 1024 + (k0) + ((sl ^ (row & 7)) << 3),         \
                    Asl + (buf) * 8192 + i * 2048 + w * 512);                               \
        }                                                                                   \
    }
#define GSW(k0)                                                                             \
    {                                                                                       \
        _Pragma("unroll")                                                                   \
        for (int i = 0; i < 4; ++i) {                                                       \
            int off = i * 4096 + w * 1024 + lane * 16;                                      \
            int row = off >> 7, sl = (off >> 4) & 7;                                        \
            gload16(W + (size_t)(bn + row) * 1024 + (k0) + ((sl ^ (row & 7)) << 3),         \
                    Wsl + i * 2048 + w * 512);                                              \
        }                                                                                   \
    }

    GSA(0, 0);
    GSW(0);
    __syncthreads();
    int cur = 0;

    for (int k0 = 0; k0 < 1024; k0 += 64) {
        if (k0 < 960) GSA(cur ^ 1, k0 + 64);   // A prefetch hides under compute
        #pragma unroll
        for (int ks = 0; ks < 2; ++ks) {
            bf16x8 af[4], bfr[4];
            #pragma unroll
            for (int rf = 0; rf < 4; ++rf) {
                int row = wr + rf * 16 + c;
                int col = (ks * 64 + g * 16) ^ ((row & 7) << 4);
                af[rf] = *(const bf16x8*)((const char*)Asl + cur * 16384 + row * 128 + col);
            }
            #pragma unroll
            for (int cf = 0; cf < 4; ++cf) {
                int row = wc + cf * 16 + c;
                int col = (ks * 64 + g * 16) ^ ((row & 7) << 4);
                bfr[cf] = *(const bf16x8*)((const char*)Wsl + row * 128 + col);
            }
            __builtin_amdgcn_s_setprio(1);
            #pragma unroll
            for (int rf = 0; rf < 4; ++rf)
                #pragma unroll
                for (int cf = 0; cf < 4; ++cf)
                    acc[rf][cf] = MFMA16(af[rf], bfr[cf], acc[rf][cf]);
            __builtin_amdgcn_s_setprio(0);
        }
        __syncthreads();                        // Wsl free; A prefetch drained
        if (k0 < 960) {
            GSW(k0 + 64);                       // exposed W stage (L2-hit); cross-block MFMA covers
            __syncthreads();
        }
        cur ^= 1;
    }
#undef GSA
#undef GSW

    if (MODE == 2) {
        // transposed per-head epilogue, two 64-d rounds through LDS [64][136]
        const int bb = bm >> 11, sb = bm & 2047;
        #pragma unroll
        for (int rd = 0; rd < 2; ++rd) {
            __syncthreads();
            if ((w & 1) == rd) {
                #pragma unroll
                for (int cf = 0; cf < 4; ++cf) {
                    int dl = cf * 16 + c;
                    float bv = bias[bn + rd * 64 + dl];
                    #pragma unroll
                    for (int rf = 0; rf < 4; ++rf) {
                        unsigned p0 = cvtpk(acc[rf][cf][0] + bv, acc[rf][cf][1] + bv);
                        unsigned p1 = cvtpk(acc[rf][cf][2] + bv, acc[rf][cf][3] + bv);
                        *(uint2*)&gsm[dl * 136 + wr + rf * 16 + 4 * g] = make_uint2(p0, p1);
                    }
                }
            }
            __syncthreads();
            const int hrd = (bn >> 6) + rd;
            #pragma unroll
            for (int i = 0; i < 4; ++i) {
                int idx = i * 256 + t;
                int d = idx >> 4, ch = idx & 15;
                bf16x8 vv = *(const bf16x8*)&gsm[d * 136 + ch * 8];
                *(bf16x8*)(Cout + ((size_t)((bb * 16 + hrd) * 64 + d)) * 2048 + sb + ch * 8) = vv;
            }
        }
        return;
    }

    #pragma unroll
    for (int rf = 0; rf < 4; ++rf) {
        #pragma unroll
        for (int cf = 0; cf < 4; ++cf) {
            int nCol = bn + wc + cf * 16 + c;
            float bv = bias[nCol];
            #pragma unroll
            for (int r = 0; r < 4; ++r) {
                int row = bm + wr + rf * 16 + 4 * g + r;
                Cout[(size_t)row * 1024 + nCol] = f2bf((acc[rf][cf][r] + bv) * scale);
            }
        }
    }
}

// Q/K/V projections, 128x128 tiles, 1D grid XCD-chunked: 768 blocks, 3/CU.
__global__ __launch_bounds__(256)
void gemm_qkv(const u16* __restrict__ Ab, const u16* __restrict__ Wb,
              const float* __restrict__ b0, const float* __restrict__ b1, const float* __restrict__ b2,
              u16* __restrict__ Qp, u16* __restrict__ Kp, u16* __restrict__ Vtb, float qscale) {
    __shared__ u16 gsm[24576];   // 48KB
    int id = blockIdx.x;
    int xcd = id & 7, r = id >> 3;       // r: 0..95
    int z = r >> 5, rr = r & 31;
    int bm = (xcd * 4 + (rr >> 3)) * 128;
    int bn = (rr & 7) * 128;
    if (z == 0)      gemm_body2<0>(gsm, Ab,           Wb,           b0, Qp,  qscale, bm, bn);
    else if (z == 1) gemm_body2<0>(gsm, Ab + 4194304, Wb + 1048576, b1, Kp,  1.f, bm, bn);
    else             gemm_body2<2>(gsm, Ab + 8388608, Wb + 2097152, b2, Vtb, 1.f, bm, bn);
}

__global__ __launch_bounds__(256)
void gemm_o(const u16* __restrict__ A, const u16* __restrict__ W,
            const float* __restrict__ bias, float* __restrict__ out) {
    __shared__ u16 gsm[24576];
    int id = blockIdx.x;
    int xcd = id & 7, r = id >> 3;       // r: 0..63
    int bm = (xcd * 4 + (r >> 4)) * 128;
    int bn = (r & 15) * 64;
    gemm_body(gsm, A, W, bias, out, bm, bn);
}

// ---- MFMA flash attention: 32x32 MFMA, 8 waves, split-K, T15 software pipeline ----
// Q pre-scaled by SCALE*log2e; p = exp2(s) unnormalized; l via ones-MFMA.
// VALU diet: bare v_exp_f32, persistent zero C-tuple, hoisted stage addressing.
// LDS: K [half][2][4096 u16] = 32KB ; V [half][3][4096 u16] = 48KB ; total 80KB.
__global__ __launch_bounds__(512, 4)
void attn_mfma(const u16* __restrict__ Qp, const u16* __restrict__ Kp,
               const u16* __restrict__ Vt, u16* __restrict__ AO) {
    __shared__ u16 smem[40960];

    const int t = threadIdx.x, lane = t & 63, w = t >> 6;
    const int wl = w & 3, half = w >> 2;
    const int c5 = lane & 31, hf = lane >> 5;

    // XCD-aware decode: 4 whole heads per XCD
    const int id = blockIdx.x;
    const int xcd = id & 7, slot = id >> 3;
    const int hd = xcd * 4 + (slot >> 4);
    const int b = hd >> 4, h = hd & 15;
    const int qw = (slot & 15) * 128 + wl * 32;

    // Q B-operand frags: lane holds Q[qw+c5][ks*16 + hf*8 ..+8]
    bf16x8 qfr[4];
    #pragma unroll
    for (int ks = 0; ks < 4; ++ks)
        qfr[ks] = *(const bf16x8*)(Qp + (size_t)(b * 2048 + qw + c5) * 1024 + h * 64 + ks * 16 + hf * 8);

    f32x16 oacc[2], lacc, z16;
    #pragma unroll
    for (int j = 0; j < 16; ++j) { oacc[0][j] = 0.f; oacc[1][j] = 0.f; lacc[j] = 0.f; z16[j] = 0.f; }

    bf16x8 ones;
    #pragma unroll
    for (int j = 0; j < 8; ++j) ones[j] = (short)0x3F80;

    // hoisted staging bases (per-thread; swizzle computed once)
    const int srow = t >> 3, ssl = t & 7;
    const int sswz = (ssl ^ (srow & 7)) << 3;
    const u16* kbase0 = Kp + (size_t)(b * 2048 + srow) * 1024 + h * 64 + sswz;
    const u16* vbase0 = Vt + ((size_t)((b * 16 + h) * 64 + srow)) * 2048 + sswz;

    // stage one 64-key tile for each half (i=0: lo tile `it`, i=1: hi tile `16+it`)
#define STAGE(kbuf, vbuf, it)                                                                       \
    {                                                                                               \
        _Pragma("unroll")                                                                           \
        for (int i = 0; i < 2; ++i) {                                                               \
            int kti = i * 16 + (it);                                                                \
            gload16(kbase0 + (size_t)kti * 65536, smem + i * 8192 + (kbuf) * 4096 + w * 512);       \
            gload16(vbase0 + kti * 64, smem + 16384 + i * 12288 + (vbuf) * 4096 + w * 512);         \
        }                                                                                           \
    }

    // QKT for sub-tile kf of current K tile -> s (first MFMA consumes persistent zero tuple)
#define QKT(kbase, kf, s)                                                                           \
    {                                                                                               \
        const int krow = (kf) * 32 + c5;                                                            \
        const int ksw = (krow & 7) << 4;                                                            \
        bf16x8 ka0 = *(const bf16x8*)((kbase) + krow * 128 + ((hf * 16) ^ ksw));                    \
        (s) = MFMA32(ka0, qfr[0], z16);                                                             \
        _Pragma("unroll")                                                                           \
        for (int ks = 1; ks < 4; ++ks) {                                                            \
            bf16x8 ka = *(const bf16x8*)((kbase) + krow * 128 + ((ks * 32 + hf * 16) ^ ksw));       \
            (s) = MFMA32(ka, qfr[ks], (s));                                                         \
        }                                                                                           \
    }

    // softmax numerator + pack + exchange: s -> (pv0, pv1) B-operands
#define SM(s, pv0, pv1)                                                                             \
    {                                                                                               \
        _Pragma("unroll")                                                                           \
        for (int j = 0; j < 16; ++j) (s)[j] = fexp2((s)[j]);                                        \
        unsigned wd[8];                                                                             \
        _Pragma("unroll")                                                                           \
        for (int j = 0; j < 8; ++j) wd[j] = cvtpk((s)[2 * j], (s)[2 * j + 1]);                      \
        union { unsigned u[4]; bf16x8 v; } a0, a1;                                                  \
        xhalf(wd[0], wd[2], hf, a0.u[0], a0.u[2]);                                                  \
        xhalf(wd[1], wd[3], hf, a0.u[1], a0.u[3]);                                                  \
        xhalf(wd[4], wd[6], hf, a1.u[0], a1.u[2]);                                                  \
        xhalf(wd[5], wd[7], hf, a1.u[1], a1.u[3]);                                                  \
        (pv0) = a0.v; (pv1) = a1.v;                                                                 \
    }

    // PV accumulate for sub-tile kf with operands (pv0, pv1) against V at vbase
#define PVOP(vbase, kf, pv0, pv1)                                                                   \
    {                                                                                               \
        _Pragma("unroll")                                                                           \
        for (int pp = 0; pp < 2; ++pp) {                                                            \
            bf16x8 pB = pp ? (pv1) : (pv0);                                                         \
            const int kc = (kf) * 64 + pp * 32 + hf * 16;                                           \
            _Pragma("unroll")                                                                       \
            for (int df = 0; df < 2; ++df) {                                                        \
                int vrow = df * 32 + c5;                                                            \
                bf16x8 va = *(const bf16x8*)((vbase) + vrow * 128 + (kc ^ ((vrow & 7) << 4)));      \
                oacc[df] = MFMA32(va, pB, oacc[df]);                                                \
            }                                                                                       \
            lacc = MFMA32(ones, pB, lacc);                                                          \
        }                                                                                           \
    }

    STAGE(0, 0, 0);
    __syncthreads();

    const char* smb = (const char*)smem;
    const char* vreg = smb + 32768 + half * 24576;   // V region byte base for this half
    int cur2 = 0, cur3 = 0, nxt3 = 1, prv3 = 2;
    bf16x8 pc0, pc1;   // carried kf1 pack from previous tile

    for (int it = 0; it < 16; ++it) {
        if (it < 15) STAGE(cur2 ^ 1, nxt3, it + 1);
        const char* kbase = smb + half * 16384 + cur2 * 8192;
        const char* vcur = vreg + cur3 * 8192;
        const char* vprev = vreg + prv3 * 8192;

        f32x16 s0;
        __builtin_amdgcn_s_setprio(1);
        QKT(kbase, 0, s0);
        if (it) PVOP(vprev, 1, pc0, pc1);      // independent MFMA cluster covers s0 latency
        __builtin_amdgcn_s_setprio(0);

        bf16x8 b00, b01;
        SM(s0, b00, b01);

        f32x16 s1;
        __builtin_amdgcn_s_setprio(1);
        QKT(kbase, 1, s1);
        PVOP(vcur, 0, b00, b01);               // covers s1 latency
        __builtin_amdgcn_s_setprio(0);

        SM(s1, pc0, pc1);                      // carried to next iteration

        __syncthreads();
        prv3 = cur3; cur3 = nxt3; nxt3 = (nxt3 == 2) ? 0 : nxt3 + 1;
        cur2 ^= 1;
    }
    // drain: final kf1 PV (V tile 15 lives at prv3)
    {
        const char* vprev = vreg + prv3 * 8192;
        PVOP(vprev, 1, pc0, pc1);
    }

    // ---- split-K combine: hi waves deposit partials; lo waves add + normalize + store ----
    __syncthreads();
    float* fs = (float*)smem;
    const int pbase = wl * 2112;   // per-pair region: 2048 f32 oacc + 64 f32 l
    if (half) {
        #pragma unroll
        for (int df = 0; df < 2; ++df)
            #pragma unroll
            for (int j = 0; j < 16; ++j)
                fs[pbase + (df * 16 + j) * 64 + lane] = oacc[df][j];
        fs[pbase + 2048 + lane] = lacc[0];
    }
    __syncthreads();
    if (!half) {
        #pragma unroll
        for (int df = 0; df < 2; ++df)
            #pragma unroll
            for (int j = 0; j < 16; ++j)
                oacc[df][j] += fs[pbase + (df * 16 + j) * 64 + lane];
        const float inv = 1.f / (lacc[0] + fs[pbase + 2048 + lane]);

        char* pw = (char*)smem + 33792 + wl * 4096;   // 32 q x 128 B per lo-wave
        #pragma unroll
        for (int df = 0; df < 2; ++df)
            #pragma unroll
            for (int rq = 0; rq < 4; ++rq) {
                unsigned p0 = cvtpk(oacc[df][rq * 4 + 0] * inv, oacc[df][rq * 4 + 1] * inv);
                unsigned p1 = cvtpk(oacc[df][rq * 4 + 2] * inv, oacc[df][rq * 4 + 3] * inv);
                int dbyte = df * 64 + rq * 16 + hf * 8;
                *(uint2*)(pw + c5 * 128 + (dbyte ^ ((c5 & 7) << 4))) = make_uint2(p0, p1);
            }
        // wave-local repack: no barrier needed
        #pragma unroll
        for (int i = 0; i < 4; ++i) {
            int fl = lane + 64 * i;
            int q = fl >> 3, ch = fl & 7;
            bf16x8 vv = *(const bf16x8*)(pw + q * 128 + ((ch * 16) ^ ((q & 7) << 4)));
            *(bf16x8*)(AO + (size_t)(b * 2048 + qw + q) * 1024 + h * 64 + ch * 8) = vv;
        }
    }
}

extern "C" void kernel_launch(void* const* d_in, const int* in_sizes, int n_in,
                              void* d_out, int out_size, void* d_ws, size_t ws_size,
                              hipStream_t stream) {
    const float* q  = (const float*)d_in[0];
    const float* k  = (const float*)d_in[1];
    const float* v  = (const float*)d_in[2];
    const float* Wq = (const float*)d_in[3];
    const float* bq = (const float*)d_in[4];
    const float* Wk = (const float*)d_in[5];
    const float* bk = (const float*)d_in[6];
    const float* Wv = (const float*)d_in[7];
    const float* bv = (const float*)d_in[8];
    const float* Wo = (const float*)d_in[9];
    const float* bo = (const float*)d_in[10];

    const size_t NE = 4194304;  // B*S*D
    u16* ws = (u16*)d_ws;
    u16* xq = ws;                // bf16 q input
    u16* xk = ws + NE;           // bf16 k input   (reused: AO after QKV GEMMs)
    u16* xv = ws + 2 * NE;       // bf16 v input
    u16* Wb = ws + 3 * NE;       // 4 x 1M bf16 weights
    u16* Qp = ws + 4 * NE;
    u16* Kp = ws + 5 * NE;
    u16* Vtb = ws + 6 * NE;      // transposed V, written directly by V-GEMM
    u16* AO = xk;

    const float CS = 0.125f * 1.4426950408889634f;  // SCALE * log2(e)

    cvt_all<<<8192, 256, 0, stream>>>(q, k, v, Wq, Wk, Wv, Wo, xq, xk, xv, Wb);

    gemm_qkv<<<768, 256, 0, stream>>>(ws, Wb, bq, bk, bv, Qp, Kp, Vtb, CS);

    attn_mfma<<<512, 512, 0, stream>>>(Qp, Kp, Vtb, AO);

    gemm_o<<<512, 256, 0, stream>>>(AO, Wb + 3145728, bo, (float*)d_out);
}

// Round 16
// 103.795 us; speedup vs baseline: 1.0607x; 1.0607x over previous
//
#include <hip/hip_runtime.h>
#include <hip/hip_bf16.h>

typedef __attribute__((ext_vector_type(8))) short bf16x8;
typedef __attribute__((ext_vector_type(4))) float f32x4;
typedef __attribute__((ext_vector_type(16))) float f32x16;
typedef unsigned short u16;

#define MFMA16(A,B,C) __builtin_amdgcn_mfma_f32_16x16x32_bf16(A,B,C,0,0,0)
#define MFMA32(A,B,C) __builtin_amdgcn_mfma_f32_32x32x16_bf16(A,B,C,0,0,0)

__device__ __forceinline__ u16 f2bf(float f) {
    union { float f; unsigned u; } x{f};
    unsigned r = x.u + 0x7FFFu + ((x.u >> 16) & 1u);
    return (u16)(r >> 16);
}

__device__ __forceinline__ unsigned cvtpk(float lo, float hi) {
    unsigned r;
    asm("v_cvt_pk_bf16_f32 %0, %1, %2" : "=v"(r) : "v"(lo), "v"(hi));
    return r;
}

__device__ __forceinline__ float fexp2(float x) {
#if __has_builtin(__builtin_amdgcn_exp2f)
    return __builtin_amdgcn_exp2f(x);   // bare v_exp_f32; inputs |x|<~30, no denormal path needed
#else
    return exp2f(x);
#endif
}

__device__ __forceinline__ void gload16(const void* src, void* dst) {
    __builtin_amdgcn_global_load_lds((const __attribute__((address_space(1))) void*)src,
                                     (__attribute__((address_space(3))) void*)dst, 16, 0, 0);
}

// cross-half exchange: j0 = [lo.low32 | hi2.low32], j2 = [lo.high32 | hi2.high32]
__device__ __forceinline__ void xhalf(unsigned lo, unsigned hi2, int hf, unsigned& j0, unsigned& j2) {
#if __has_builtin(__builtin_amdgcn_permlane32_swap)
    auto r = __builtin_amdgcn_permlane32_swap(lo, hi2, false, false);
    j0 = r[0]; j2 = r[1];
#else
    unsigned olo = (unsigned)__shfl_xor((int)lo, 32);
    unsigned ohi = (unsigned)__shfl_xor((int)hi2, 32);
    j0 = hf ? ohi : lo;
    j2 = hf ? hi2 : olo;
#endif
}

// ---- single fused f32 -> bf16 converter: inputs (3x 4M) + weights (4x 1M) ----
__global__ __launch_bounds__(256)
void cvt_all(const float* __restrict__ q, const float* __restrict__ k, const float* __restrict__ v,
             const float* __restrict__ Wq, const float* __restrict__ Wk,
             const float* __restrict__ Wv, const float* __restrict__ Wo,
             u16* __restrict__ oq, u16* __restrict__ ok, u16* __restrict__ ov,
             u16* __restrict__ ow) {
    int blk = blockIdx.x;
    const float* s;
    u16* o;
    if (blk < 6144) {
        int which = blk >> 11, lb = blk & 2047;
        s = (which == 0 ? q : (which == 1 ? k : v)) + (size_t)lb * 2048;
        o = (which == 0 ? oq : (which == 1 ? ok : ov)) + (size_t)lb * 2048;
    } else {
        int wblk = blk - 6144;          // 0..2047
        int which = wblk >> 9, lb = wblk & 511;
        s = (which == 0 ? Wq : (which == 1 ? Wk : (which == 2 ? Wv : Wo))) + (size_t)lb * 2048;
        o = ow + (size_t)which * 1048576 + (size_t)lb * 2048;
    }
    size_t base = (size_t)threadIdx.x * 8;
    float4 v0 = *(const float4*)(s + base);
    float4 v1 = *(const float4*)(s + base + 4);
    bf16x8 rv;
    rv[0] = (short)f2bf(v0.x); rv[1] = (short)f2bf(v0.y); rv[2] = (short)f2bf(v0.z); rv[3] = (short)f2bf(v0.w);
    rv[4] = (short)f2bf(v1.x); rv[5] = (short)f2bf(v1.y); rv[6] = (short)f2bf(v1.z); rv[7] = (short)f2bf(v1.w);
    *(bf16x8*)(o + base) = rv;
}

// ---- bf16 MFMA GEMM body: 128x64 tile, BK=64, double-buffered, prefetch-first ----
// (used by gemm_o: 512-block grid keeps 3 blocks/CU)
__device__ __forceinline__ void gemm_body(u16* gsm, const u16* __restrict__ A, const u16* __restrict__ W,
                                          const float* __restrict__ bias, float* __restrict__ Cout,
                                          int bm, int bn) {
    u16* Asl = gsm;            // 2 x 8192 u16
    u16* Wsl = gsm + 16384;    // 2 x 4096 u16
    const int t = threadIdx.x;
    const int lane = t & 63, w = t >> 6;
    const int g = lane >> 4, c = lane & 15;
    const int wr = (w >> 1) * 64, wc = (w & 1) * 32;

    f32x4 acc[4][2];
    #pragma unroll
    for (int i = 0; i < 4; ++i) {
        acc[i][0] = f32x4{0.f, 0.f, 0.f, 0.f};
        acc[i][1] = f32x4{0.f, 0.f, 0.f, 0.f};
    }

#define GS(buf, k0)                                                                         \
    {                                                                                       \
        _Pragma("unroll")                                                                   \
        for (int i = 0; i < 4; ++i) {                                                       \
            int off = i * 4096 + w * 1024 + lane * 16;                                      \
            int row = off >> 7, sl = (off >> 4) & 7;                                        \
            gload16(A + (size_t)(bm + row) * 1024 + (k0) + ((sl ^ (row & 7)) << 3),         \
                    Asl + (buf) * 8192 + i * 2048 + w * 512);                               \
        }                                                                                   \
        _Pragma("unroll")                                                                   \
        for (int i = 0; i < 2; ++i) {                                                       \
            int off = i * 4096 + w * 1024 + lane * 16;                                      \
            int row = off >> 7, sl = (off >> 4) & 7;                                        \
            gload16(W + (size_t)(bn + row) * 1024 + (k0) + ((sl ^ (row & 7)) << 3),         \
                    Wsl + (buf) * 4096 + i * 2048 + w * 512);                               \
        }                                                                                   \
    }

    GS(0, 0);
    __syncthreads();
    int cur = 0;

    for (int k0 = 0; k0 < 1024; k0 += 64) {
        if (k0 < 960) GS(cur ^ 1, k0 + 64);
        #pragma unroll
        for (int ks = 0; ks < 2; ++ks) {
            bf16x8 af[4], bfr[2];
            #pragma unroll
            for (int rf = 0; rf < 4; ++rf) {
                int row = wr + rf * 16 + c;
                int col = (ks * 64 + g * 16) ^ ((row & 7) << 4);
                af[rf] = *(const bf16x8*)((const char*)Asl + cur * 16384 + row * 128 + col);
            }
            #pragma unroll
            for (int cf = 0; cf < 2; ++cf) {
                int row = wc + cf * 16 + c;
                int col = (ks * 64 + g * 16) ^ ((row & 7) << 4);
                bfr[cf] = *(const bf16x8*)((const char*)Wsl + cur * 8192 + row * 128 + col);
            }
            __builtin_amdgcn_s_setprio(1);
            #pragma unroll
            for (int rf = 0; rf < 4; ++rf)
                #pragma unroll
                for (int cf = 0; cf < 2; ++cf)
                    acc[rf][cf] = MFMA16(af[rf], bfr[cf], acc[rf][cf]);
            __builtin_amdgcn_s_setprio(0);
        }
        __syncthreads();
        cur ^= 1;
    }
#undef GS

    #pragma unroll
    for (int rf = 0; rf < 4; ++rf) {
        #pragma unroll
        for (int cf = 0; cf < 2; ++cf) {
            int nCol = bn + wc + cf * 16 + c;
            float bv = bias[nCol];
            #pragma unroll
            for (int r = 0; r < 4; ++r) {
                int row = bm + wr + rf * 16 + 4 * g + r;
                Cout[(size_t)row * 1024 + nCol] = acc[rf][cf][r] + bv;
            }
        }
    }
}

// ---- bf16 MFMA GEMM body 2: 128x128 tile, BK=64, dbuf, 4 waves x 64x64 micro-tile ----
// (round-14 measured best: 64KB LDS, 2 blocks/CU)
// MODE: 0 = bf16 out (scaled), 2 = bf16 per-head-transposed out (Vt layout).
template<int MODE>
__device__ __forceinline__ void gemm_body2(u16* gsm, const u16* __restrict__ A, const u16* __restrict__ W,
                                           const float* __restrict__ bias, u16* __restrict__ Cout,
                                           float scale, int bm, int bn) {
    u16* Asl = gsm;            // 2 x 8192 u16 (16KB per buf)
    u16* Wsl = gsm + 16384;    // 2 x 8192 u16
    const int t = threadIdx.x;
    const int lane = t & 63, w = t >> 6;
    const int g = lane >> 4, c = lane & 15;
    const int wr = (w >> 1) * 64, wc = (w & 1) * 64;

    f32x4 acc[4][4];
    #pragma unroll
    for (int i = 0; i < 4; ++i)
        #pragma unroll
        for (int j = 0; j < 4; ++j) acc[i][j] = f32x4{0.f, 0.f, 0.f, 0.f};

#define GS2(buf, k0)                                                                        \
    {                                                                                       \
        _Pragma("unroll")                                                                   \
        for (int i = 0; i < 4; ++i) {                                                       \
            int off = i * 4096 + w * 1024 + lane * 16;                                      \
            int row = off >> 7, sl = (off >> 4) & 7;                                        \
            gload16(A + (size_t)(bm + row) * 1024 + (k0) + ((sl ^ (row & 7)) << 3),         \
                    Asl + (buf) * 8192 + i * 2048 + w * 512);                               \
            gload16(W + (size_t)(bn + row) * 1024 + (k0) + ((sl ^ (row & 7)) << 3),         \
                    Wsl + (buf) * 8192 + i * 2048 + w * 512);                               \
        }                                                                                   \
    }

    GS2(0, 0);
    __syncthreads();
    int cur = 0;

    for (int k0 = 0; k0 < 1024; k0 += 64) {
        if (k0 < 960) GS2(cur ^ 1, k0 + 64);
        #pragma unroll
        for (int ks = 0; ks < 2; ++ks) {
            bf16x8 af[4], bfr[4];
            #pragma unroll
            for (int rf = 0; rf < 4; ++rf) {
                int row = wr + rf * 16 + c;
                int col = (ks * 64 + g * 16) ^ ((row & 7) << 4);
                af[rf] = *(const bf16x8*)((const char*)Asl + cur * 16384 + row * 128 + col);
            }
            #pragma unroll
            for (int cf = 0; cf < 4; ++cf) {
                int row = wc + cf * 16 + c;
                int col = (ks * 64 + g * 16) ^ ((row & 7) << 4);
                bfr[cf] = *(const bf16x8*)((const char*)Wsl + cur * 16384 + row * 128 + col);
            }
            __builtin_amdgcn_s_setprio(1);
            #pragma unroll
            for (int rf = 0; rf < 4; ++rf)
                #pragma unroll
                for (int cf = 0; cf < 4; ++cf)
                    acc[rf][cf] = MFMA16(af[rf], bfr[cf], acc[rf][cf]);
            __builtin_amdgcn_s_setprio(0);
        }
        __syncthreads();
        cur ^= 1;
    }
#undef GS2

    if (MODE == 2) {
        // transposed per-head epilogue, two 64-d rounds through LDS [64][136]
        const int bb = bm >> 11, sb = bm & 2047;
        #pragma unroll
        for (int rd = 0; rd < 2; ++rd) {
            __syncthreads();
            if ((w & 1) == rd) {
                #pragma unroll
                for (int cf = 0; cf < 4; ++cf) {
                    int dl = cf * 16 + c;
                    float bv = bias[bn + rd * 64 + dl];
                    #pragma unroll
                    for (int rf = 0; rf < 4; ++rf) {
                        unsigned p0 = cvtpk(acc[rf][cf][0] + bv, acc[rf][cf][1] + bv);
                        unsigned p1 = cvtpk(acc[rf][cf][2] + bv, acc[rf][cf][3] + bv);
                        *(uint2*)&gsm[dl * 136 + wr + rf * 16 + 4 * g] = make_uint2(p0, p1);
                    }
                }
            }
            __syncthreads();
            const int hrd = (bn >> 6) + rd;
            #pragma unroll
            for (int i = 0; i < 4; ++i) {
                int idx = i * 256 + t;
                int d = idx >> 4, ch = idx & 15;
                bf16x8 vv = *(const bf16x8*)&gsm[d * 136 + ch * 8];
                *(bf16x8*)(Cout + ((size_t)((bb * 16 + hrd) * 64 + d)) * 2048 + sb + ch * 8) = vv;
            }
        }
        return;
    }

    #pragma unroll
    for (int rf = 0; rf < 4; ++rf) {
        #pragma unroll
        for (int cf = 0; cf < 4; ++cf) {
            int nCol = bn + wc + cf * 16 + c;
            float bv = bias[nCol];
            #pragma unroll
            for (int r = 0; r < 4; ++r) {
                int row = bm + wr + rf * 16 + 4 * g + r;
                Cout[(size_t)row * 1024 + nCol] = f2bf((acc[rf][cf][r] + bv) * scale);
            }
        }
    }
}

// Q/K/V projections, 128x128 tiles, 1D grid XCD-chunked: 768 blocks.
__global__ __launch_bounds__(256)
void gemm_qkv(const u16* __restrict__ Ab, const u16* __restrict__ Wb,
              const float* __restrict__ b0, const float* __restrict__ b1, const float* __restrict__ b2,
              u16* __restrict__ Qp, u16* __restrict__ Kp, u16* __restrict__ Vtb, float qscale) {
    __shared__ u16 gsm[32768];   // 64KB
    int id = blockIdx.x;
    int xcd = id & 7, r = id >> 3;       // r: 0..95
    int z = r >> 5, rr = r & 31;
    int bm = (xcd * 4 + (rr >> 3)) * 128;
    int bn = (rr & 7) * 128;
    if (z == 0)      gemm_body2<0>(gsm, Ab,           Wb,           b0, Qp,  qscale, bm, bn);
    else if (z == 1) gemm_body2<0>(gsm, Ab + 4194304, Wb + 1048576, b1, Kp,  1.f, bm, bn);
    else             gemm_body2<2>(gsm, Ab + 8388608, Wb + 2097152, b2, Vtb, 1.f, bm, bn);
}

__global__ __launch_bounds__(256)
void gemm_o(const u16* __restrict__ A, const u16* __restrict__ W,
            const float* __restrict__ bias, float* __restrict__ out) {
    __shared__ u16 gsm[24576];
    int id = blockIdx.x;
    int xcd = id & 7, r = id >> 3;       // r: 0..63
    int bm = (xcd * 4 + (r >> 4)) * 128;
    int bn = (r & 15) * 64;
    gemm_body(gsm, A, W, bias, out, bm, bn);
}

// ---- MFMA flash attention: 32x32 MFMA, 8 waves, split-K, T15 software pipeline ----
// Q pre-scaled by SCALE*log2e; p = exp2(s) unnormalized; l via ones-MFMA.
// VALU diet: bare v_exp_f32, persistent zero C-tuple, hoisted stage addressing.
// LDS: K [half][2][4096 u16] = 32KB ; V [half][3][4096 u16] = 48KB ; total 80KB.
__global__ __launch_bounds__(512, 4)
void attn_mfma(const u16* __restrict__ Qp, const u16* __restrict__ Kp,
               const u16* __restrict__ Vt, u16* __restrict__ AO) {
    __shared__ u16 smem[40960];

    const int t = threadIdx.x, lane = t & 63, w = t >> 6;
    const int wl = w & 3, half = w >> 2;
    const int c5 = lane & 31, hf = lane >> 5;

    // XCD-aware decode: 4 whole heads per XCD
    const int id = blockIdx.x;
    const int xcd = id & 7, slot = id >> 3;
    const int hd = xcd * 4 + (slot >> 4);
    const int b = hd >> 4, h = hd & 15;
    const int qw = (slot & 15) * 128 + wl * 32;

    // Q B-operand frags: lane holds Q[qw+c5][ks*16 + hf*8 ..+8]
    bf16x8 qfr[4];
    #pragma unroll
    for (int ks = 0; ks < 4; ++ks)
        qfr[ks] = *(const bf16x8*)(Qp + (size_t)(b * 2048 + qw + c5) * 1024 + h * 64 + ks * 16 + hf * 8);

    f32x16 oacc[2], lacc, z16;
    #pragma unroll
    for (int j = 0; j < 16; ++j) { oacc[0][j] = 0.f; oacc[1][j] = 0.f; lacc[j] = 0.f; z16[j] = 0.f; }

    bf16x8 ones;
    #pragma unroll
    for (int j = 0; j < 8; ++j) ones[j] = (short)0x3F80;

    // hoisted staging bases (per-thread; swizzle computed once)
    const int srow = t >> 3, ssl = t & 7;
    const int sswz = (ssl ^ (srow & 7)) << 3;
    const u16* kbase0 = Kp + (size_t)(b * 2048 + srow) * 1024 + h * 64 + sswz;
    const u16* vbase0 = Vt + ((size_t)((b * 16 + h) * 64 + srow)) * 2048 + sswz;

    // stage one 64-key tile for each half (i=0: lo tile `it`, i=1: hi tile `16+it`)
#define STAGE(kbuf, vbuf, it)                                                                       \
    {                                                                                               \
        _Pragma("unroll")                                                                           \
        for (int i = 0; i < 2; ++i) {                                                               \
            int kti = i * 16 + (it);                                                                \
            gload16(kbase0 + (size_t)kti * 65536, smem + i * 8192 + (kbuf) * 4096 + w * 512);       \
            gload16(vbase0 + kti * 64, smem + 16384 + i * 12288 + (vbuf) * 4096 + w * 512);         \
        }                                                                                           \
    }

    // QKT for sub-tile kf of current K tile -> s (first MFMA consumes persistent zero tuple)
#define QKT(kbase, kf, s)                                                                           \
    {                                                                                               \
        const int krow = (kf) * 32 + c5;                                                            \
        const int ksw = (krow & 7) << 4;                                                            \
        bf16x8 ka0 = *(const bf16x8*)((kbase) + krow * 128 + ((hf * 16) ^ ksw));                    \
        (s) = MFMA32(ka0, qfr[0], z16);                                                             \
        _Pragma("unroll")                                                                           \
        for (int ks = 1; ks < 4; ++ks) {                                                            \
            bf16x8 ka = *(const bf16x8*)((kbase) + krow * 128 + ((ks * 32 + hf * 16) ^ ksw));       \
            (s) = MFMA32(ka, qfr[ks], (s));                                                         \
        }                                                                                           \
    }

    // softmax numerator + pack + exchange: s -> (pv0, pv1) B-operands
#define SM(s, pv0, pv1)                                                                             \
    {                                                                                               \
        _Pragma("unroll")                                                                           \
        for (int j = 0; j < 16; ++j) (s)[j] = fexp2((s)[j]);                                        \
        unsigned wd[8];                                                                             \
        _Pragma("unroll")                                                                           \
        for (int j = 0; j < 8; ++j) wd[j] = cvtpk((s)[2 * j], (s)[2 * j + 1]);                      \
        union { unsigned u[4]; bf16x8 v; } a0, a1;                                                  \
        xhalf(wd[0], wd[2], hf, a0.u[0], a0.u[2]);                                                  \
        xhalf(wd[1], wd[3], hf, a0.u[1], a0.u[3]);                                                  \
        xhalf(wd[4], wd[6], hf, a1.u[0], a1.u[2]);                                                  \
        xhalf(wd[5], wd[7], hf, a1.u[1], a1.u[3]);                                                  \
        (pv0) = a0.v; (pv1) = a1.v;                                                                 \
    }

    // PV accumulate for sub-tile kf with operands (pv0, pv1) against V at vbase
#define PVOP(vbase, kf, pv0, pv1)                                                                   \
    {                                                                                               \
        _Pragma("unroll")                                                                           \
        for (int pp = 0; pp < 2; ++pp) {                                                            \
            bf16x8 pB = pp ? (pv1) : (pv0);                                                         \
            const int kc = (kf) * 64 + pp * 32 + hf * 16;                                           \
            _Pragma("unroll")                                                                       \
            for (int df = 0; df < 2; ++df) {                                                        \
                int vrow = df * 32 + c5;                                                            \
                bf16x8 va = *(const bf16x8*)((vbase) + vrow * 128 + (kc ^ ((vrow & 7) << 4)));      \
                oacc[df] = MFMA32(va, pB, oacc[df]);                                                \
            }                                                                                       \
            lacc = MFMA32(ones, pB, lacc);                                                          \
        }                                                                                           \
    }

    STAGE(0, 0, 0);
    __syncthreads();

    const char* smb = (const char*)smem;
    const char* vreg = smb + 32768 + half * 24576;   // V region byte base for this half
    int cur2 = 0, cur3 = 0, nxt3 = 1, prv3 = 2;
    bf16x8 pc0, pc1;   // carried kf1 pack from previous tile

    for (int it = 0; it < 16; ++it) {
        if (it < 15) STAGE(cur2 ^ 1, nxt3, it + 1);
        const char* kbase = smb + half * 16384 + cur2 * 8192;
        const char* vcur = vreg + cur3 * 8192;
        const char* vprev = vreg + prv3 * 8192;

        f32x16 s0;
        __builtin_amdgcn_s_setprio(1);
        QKT(kbase, 0, s0);
        if (it) PVOP(vprev, 1, pc0, pc1);      // independent MFMA cluster covers s0 latency
        __builtin_amdgcn_s_setprio(0);

        bf16x8 b00, b01;
        SM(s0, b00, b01);

        f32x16 s1;
        __builtin_amdgcn_s_setprio(1);
        QKT(kbase, 1, s1);
        PVOP(vcur, 0, b00, b01);               // covers s1 latency
        __builtin_amdgcn_s_setprio(0);

        SM(s1, pc0, pc1);                      // carried to next iteration

        __syncthreads();
        prv3 = cur3; cur3 = nxt3; nxt3 = (nxt3 == 2) ? 0 : nxt3 + 1;
        cur2 ^= 1;
    }
    // drain: final kf1 PV (V tile 15 lives at prv3)
    {
        const char* vprev = vreg + prv3 * 8192;
        PVOP(vprev, 1, pc0, pc1);
    }

    // ---- split-K combine: hi waves deposit partials; lo waves add + normalize + store ----
    __syncthreads();
    float* fs = (float*)smem;
    const int pbase = wl * 2112;   // per-pair region: 2048 f32 oacc + 64 f32 l
    if (half) {
        #pragma unroll
        for (int df = 0; df < 2; ++df)
            #pragma unroll
            for (int j = 0; j < 16; ++j)
                fs[pbase + (df * 16 + j) * 64 + lane] = oacc[df][j];
        fs[pbase + 2048 + lane] = lacc[0];
    }
    __syncthreads();
    if (!half) {
        #pragma unroll
        for (int df = 0; df < 2; ++df)
            #pragma unroll
            for (int j = 0; j < 16; ++j)
                oacc[df][j] += fs[pbase + (df * 16 + j) * 64 + lane];
        const float inv = 1.f / (lacc[0] + fs[pbase + 2048 + lane]);

        char* pw = (char*)smem + 33792 + wl * 4096;   // 32 q x 128 B per lo-wave
        #pragma unroll
        for (int df = 0; df < 2; ++df)
            #pragma unroll
            for (int rq = 0; rq < 4; ++rq) {
                unsigned p0 = cvtpk(oacc[df][rq * 4 + 0] * inv, oacc[df][rq * 4 + 1] * inv);
                unsigned p1 = cvtpk(oacc[df][rq * 4 + 2] * inv, oacc[df][rq * 4 + 3] * inv);
                int dbyte = df * 64 + rq * 16 + hf * 8;
                *(uint2*)(pw + c5 * 128 + (dbyte ^ ((c5 & 7) << 4))) = make_uint2(p0, p1);
            }
        // wave-local repack: no barrier needed
        #pragma unroll
        for (int i = 0; i < 4; ++i) {
            int fl = lane + 64 * i;
            int q = fl >> 3, ch = fl & 7;
            bf16x8 vv = *(const bf16x8*)(pw + q * 128 + ((ch * 16) ^ ((q & 7) << 4)));
            *(bf16x8*)(AO + (size_t)(b * 2048 + qw + q) * 1024 + h * 64 + ch * 8) = vv;
        }
    }
}

extern "C" void kernel_launch(void* const* d_in, const int* in_sizes, int n_in,
                              void* d_out, int out_size, void* d_ws, size_t ws_size,
                              hipStream_t stream) {
    const float* q  = (const float*)d_in[0];
    const float* k  = (const float*)d_in[1];
    const float* v  = (const float*)d_in[2];
    const float* Wq = (const float*)d_in[3];
    const float* bq = (const float*)d_in[4];
    const float* Wk = (const float*)d_in[5];
    const float* bk = (const float*)d_in[6];
    const float* Wv = (const float*)d_in[7];
    const float* bv = (const float*)d_in[8];
    const float* Wo = (const float*)d_in[9];
    const float* bo = (const float*)d_in[10];

    const size_t NE = 4194304;  // B*S*D
    u16* ws = (u16*)d_ws;
    u16* xq = ws;                // bf16 q input
    u16* xk = ws + NE;           // bf16 k input   (reused: AO after QKV GEMMs)
    u16* xv = ws + 2 * NE;       // bf16 v input
    u16* Wb = ws + 3 * NE;       // 4 x 1M bf16 weights
    u16* Qp = ws + 4 * NE;
    u16* Kp = ws + 5 * NE;
    u16* Vtb = ws + 6 * NE;      // transposed V, written directly by V-GEMM
    u16* AO = xk;

    const float CS = 0.125f * 1.4426950408889634f;  // SCALE * log2(e)

    cvt_all<<<8192, 256, 0, stream>>>(q, k, v, Wq, Wk, Wv, Wo, xq, xk, xv, Wb);

    gemm_qkv<<<768, 256, 0, stream>>>(ws, Wb, bq, bk, bv, Qp, Kp, Vtb, CS);

    attn_mfma<<<512, 512, 0, stream>>>(Qp, Kp, Vtb, AO);

    gemm_o<<<512, 256, 0, stream>>>(AO, Wb + 3145728, bo, (float*)d_out);
}